// Round 13
// baseline (128.463 us; speedup 1.0000x reference)
//
#include <hip/hip_runtime.h>
#include <math.h>

#define NPTS 512
#define NBATCH 64
#define NROWS (NPTS * NBATCH)   // 32768
#define LARGEV 1000000.0f
#define RPW 8                   // rows per wave in the MLP phases

typedef float v2f __attribute__((ext_vector_type(2)));
typedef short bf16x8 __attribute__((ext_vector_type(8)));   // 8 bf16 = 4 VGPRs
typedef float f32x4 __attribute__((ext_vector_type(4)));

__device__ __forceinline__ float rdlane(float v, int l) {
  return __uint_as_float((unsigned)__builtin_amdgcn_readlane((int)__float_as_uint(v), l));
}
__device__ __forceinline__ void pk_fma(v2f& acc, float s, v2f w) {
  acc = __builtin_elementwise_fma(w, (v2f){s, s}, acc);
}
// manual bf16 RTNE; inputs finite here
__device__ __forceinline__ unsigned short f2bf(float f) {
  unsigned u = __float_as_uint(f);
  u += 0x7FFFu + ((u >> 16) & 1u);
  return (unsigned short)(u >> 16);
}
__device__ __forceinline__ float bf2f(unsigned short h) {
  return __uint_as_float(((unsigned)h) << 16);
}

// ---------------------------------------------------------------------------
// W2 pre-split into MFMA B-fragment order (hi/lo bf16 planes in d_ws).
// (r11-verified)
// ---------------------------------------------------------------------------
__global__ __launch_bounds__(256) void w2prep(const float* __restrict__ W2,
                                              unsigned short* __restrict__ w2p) {
  const int t = blockIdx.x * 256 + threadIdx.x;   // 0..2047
  const int lane = t & 63;
  const int kk = (t >> 6) & 3;
  const int nt = t >> 8;                           // 0..7
  const int n  = nt * 16 + (lane & 15);
  const int k0 = kk * 32 + ((lane >> 4) << 3);
  unsigned hv[4], lv[4];
#pragma unroll
  for (int jp = 0; jp < 4; ++jp) {
    const float va = W2[(k0 + 2 * jp) * 128 + n];
    const float vb = W2[(k0 + 2 * jp + 1) * 128 + n];
    const unsigned short ha = f2bf(va), hb = f2bf(vb);
    const unsigned short la = f2bf(va - bf2f(ha)), lb = f2bf(vb - bf2f(hb));
    hv[jp] = (unsigned)ha | ((unsigned)hb << 16);
    lv[jp] = (unsigned)la | ((unsigned)lb << 16);
  }
  const int fi = (nt * 4 + kk) * 64 + lane;
  ((uint4*)w2p)[fi] = make_uint4(hv[0], hv[1], hv[2], hv[3]);
  ((uint4*)(w2p + 16384))[fi] = make_uint4(lv[0], lv[1], lv[2], lv[3]);
}

// ---------------------------------------------------------------------------
// Round-13 = r11 tiling (r12's 2x-blocks regressed: per-block overhead) +
// DS-pipe diet. Theory: feature loop's 4 DS ops/pair (~10K wave-ops/CU on
// the per-CU LDS pipe shared by 4 SIMDs) is the binding resource -- explains
// r8 (conflicts->0 neutral) and r9/r12 (more waves neutral).
//  - sp read as float4: 2 points per ds_read_b128 (0.5 reads/pair).
//  - dir mins -> registers, d^2 domain (sqrt(min d2) == min dist, bit-exact
//    by monotonicity of correctly-rounded sqrt; minNum drops NaN as before).
//  - sector counts -> 2 packed u32 regs (byte/sector, max 64/lane; slot 8
//    excluded by range check). Kills the count atomic.
//  - sector-min atomic now carries d2 bits (NaN -> slot 8 trash unchanged);
//    8 sqrts after the reduction instead of 64 in-loop for mins.
// Net DS: 4 -> 1.5 ops/pair. VALU +~8/pair (acceptable: VALU has headroom).
// LDS 21.5KB: scru = 9 sector-min planes (9216B) + xs (4224B); gT (17408B)
// overlays both -- safe: xreg loads complete before the post-LN barrier.
// MFMA phase 3 + phase 1 + LN byte-for-byte r11.
// ---------------------------------------------------------------------------
__global__ __launch_bounds__(256, 4) void fused_kernel(const float* __restrict__ pos,
    const void* __restrict__ kpm,
    const float* __restrict__ W1, const float* __restrict__ b1,
    const float* __restrict__ gamma, const float* __restrict__ beta,
    const unsigned short* __restrict__ w2p, const float* __restrict__ b2,
    float* __restrict__ out) {
  __shared__ __align__(16) float2 sp[NPTS];        //  4096 B
  __shared__ __align__(16) unsigned shbuf[4352];   // 17408 B (scru+xs / gT overlay)
  __shared__ int sflag, sMasked;
  unsigned* const scru = shbuf;                    // words [0,2304): 9 x 256 sector-min
  float* const xs = (float*)&shbuf[2304];          // words [2304,3360): 32x33 feats
  const int b  = blockIdx.x >> 4;
  const int i0 = (blockIdx.x & 15) << 5;
  const int tid = threadIdx.x;

  // ---- inline mask-dtype sniff over first 2KB of the raw mask buffer ----
  if (tid == 0) { sflag = 0; sMasked = 0; }
  __syncthreads();
  {
    const unsigned int* rw = (const unsigned int*)kpm;
    const unsigned int w0 = rw[tid];
    const unsigned int w1 = rw[tid + 256];
    int f = 0;
    if (w0 == 0x3f800000u || w1 == 0x3f800000u) f |= 2;
    if (w0 > 1u || w1 > 1u) f |= 1;
    if (f) atomicOr(&sflag, f);
  }
  __syncthreads();
  const int fmt = sflag;   // 2=>f32, 1=>bytes, 0=>i32

  // ---- stage positions (NaN for masked), count masked via ballot ----
  for (int t = tid; t < NPTS; t += 256) {
    bool m;
    if (fmt & 2)      m = ((const float*)kpm)[b * NPTS + t] != 0.0f;
    else if (fmt & 1) m = ((const unsigned char*)kpm)[b * NPTS + t] != 0;
    else              m = ((const int*)kpm)[b * NPTS + t] != 0;
    float2 p = ((const float2*)pos)[b * NPTS + t];
    if (m) { p.x = __builtin_nanf(""); p.y = p.x; }
    sp[t] = p;
    unsigned long long bal = __ballot(m);
    if ((tid & 63) == 0) atomicAdd(&sMasked, __popcll(bal));
  }
#pragma unroll
  for (int k = 0; k < 9; ++k) scru[k * 256 + tid] = __float_as_uint(LARGEV);
  __syncthreads();
  const int M = sMasked;

  const int il = tid >> 3;       // row within block: 0..31
  const int jc = tid & 7;        // j-chunk: 0..7
  const int i  = i0 + il;
  const float2 pi = ((const float2*)pos)[b * NPTS + i];

  const float T5 = __uint_as_float(0x41C7FFFFu);   // 25 - 2^-19
  unsigned cu = 0u, cd = 0u, asum = 0u;            // packed threshold counts
  unsigned scl = 0u, sch = 0u;                     // packed sector counts (byte each)
  float dm0 = LARGEV, dm1 = LARGEV, dm2 = LARGEV;  // dir mins in d^2 domain
  float sumd = 0.0f;
  const float4* __restrict__ sp4 = (const float4*)sp;

#pragma unroll 4
  for (int jj = 0; jj < 32; ++jj) {
    const int p = (jj << 3) + jc;          // point-pair index
    const float4 pj2 = sp4[p];             // points 2p, 2p+1
#pragma unroll
    for (int s = 0; s < 2; ++s) {
      const int j = 2 * p + s;
      const float px = s ? pj2.z : pj2.x;
      const float py = s ? pj2.w : pj2.y;
      const float dx = __fsub_rn(px, pi.x);
      const float dy = __fsub_rn(py, pi.y);
      float d2 = __fadd_rn(__fadd_rn(__fmul_rn(dx, dx), __fmul_rn(dy, dy)), 1e-8f);
      d2 = (j == i) ? __builtin_nanf("") : d2;     // self -> NaN

      const float hdy = __fmul_rn(fabsf(dy), 0.5f);
      const bool up = dx > hdy;
      const bool dn = dx < -hdy;

      const unsigned a = (d2 < 9.0f)  ? 0x01010101u
                       : ((d2 < T5)    ? 0x01010100u
                       : ((d2 < 64.0f) ? 0x01010000u
                       : ((d2 < 144.0f) ? 0x01000000u : 0u)));
      asum += a;
      cu += up ? a : 0u;
      cd += dn ? a : 0u;

      // dir mins in d^2 (NaN dropped by minNum; up/dn false on NaN)
      dm0 = fminf(dm0, up ? d2 : LARGEV);
      dm1 = fminf(dm1, dn ? d2 : LARGEV);
      dm2 = fminf(dm2, (!up && !dn) ? d2 : LARGEV);

      const float dist = __fsqrt_rn(d2);           // NaN-propagating
      sumd += (dist < 1.0e30f) ? dist : 0.0f;

      // octant sector; dy==0,dx>0 -> s4; dy==0,dx<=0 / NaN -> 8 (trash)
      const int slot = (dy > 0.0f)
          ? ((dx > 0.0f) ? ((dy < dx) ? 4 : 5) : ((-dx < dy) ? 6 : 7))
          : ((dy < 0.0f) ? ((dx < 0.0f) ? ((dx < dy) ? 0 : 1) : ((dx < -dy) ? 2 : 3))
                         : ((dx > 0.0f) ? 4 : 8));
      // packed register count (slot 8 excluded by range checks)
      const unsigned add = 1u << ((slot & 3) << 3);
      scl += (slot < 4) ? add : 0u;
      sch += ((unsigned)(slot - 4) < 4u) ? add : 0u;
      // sector min on d^2 bits (fire-and-forget; NaN never wins)
      atomicMin(&scru[slot * 256 + tid], __float_as_uint(d2));
    }
  }

  // ---- readback own sector cells + unpack ----
  const unsigned clp = asum - cu - cd;
  float cnt[12];
  cnt[0] = (float)(cu & 0xffu);  cnt[3] = (float)((cu >> 8) & 0xffu);
  cnt[6] = (float)((cu >> 16) & 0xffu);  cnt[9]  = (float)(cu >> 24);
  cnt[1] = (float)(cd & 0xffu);  cnt[4] = (float)((cd >> 8) & 0xffu);
  cnt[7] = (float)((cd >> 16) & 0xffu);  cnt[10] = (float)(cd >> 24);
  cnt[2] = (float)(clp & 0xffu); cnt[5] = (float)((clp >> 8) & 0xffu);
  cnt[8] = (float)((clp >> 16) & 0xffu); cnt[11] = (float)(clp >> 24);
  float scnt[8], smin[8];
#pragma unroll
  for (int k = 0; k < 8; ++k) {
    smin[k] = __uint_as_float(scru[k * 256 + tid]);   // d^2 partial min
    scnt[k] = (float)(((k < 4 ? scl : sch) >> ((k & 3) << 3)) & 0xffu);
  }
  float dmin[3] = {dm0, dm1, dm2};

  // ---- reduce 8 chunk partials (lanes differing in bits 0..2) ----
#pragma unroll
  for (int k = 0; k < 12; ++k) {
    cnt[k] += __shfl_xor(cnt[k], 1); cnt[k] += __shfl_xor(cnt[k], 2); cnt[k] += __shfl_xor(cnt[k], 4);
  }
#pragma unroll
  for (int k = 0; k < 8; ++k) {
    scnt[k] += __shfl_xor(scnt[k], 1); scnt[k] += __shfl_xor(scnt[k], 2); scnt[k] += __shfl_xor(scnt[k], 4);
  }
  sumd += __shfl_xor(sumd, 1); sumd += __shfl_xor(sumd, 2); sumd += __shfl_xor(sumd, 4);
#pragma unroll
  for (int k = 0; k < 3; ++k) {
    dmin[k] = fminf(dmin[k], __shfl_xor(dmin[k], 1));
    dmin[k] = fminf(dmin[k], __shfl_xor(dmin[k], 2));
    dmin[k] = fminf(dmin[k], __shfl_xor(dmin[k], 4));
  }
#pragma unroll
  for (int k = 0; k < 8; ++k) {
    smin[k] = fminf(smin[k], __shfl_xor(smin[k], 1));
    smin[k] = fminf(smin[k], __shfl_xor(smin[k], 2));
    smin[k] = fminf(smin[k], __shfl_xor(smin[k], 4));
  }

  // ---- park row il's 33 feats (same-wave handoff, r11-proven) ----
  if (jc == 0) {
    const bool own_unmasked = !isnan(sp[i].x);
    const float vcnt = fmaxf((float)(NPTS - M - (own_unmasked ? 1 : 0)), 1.0f);
    float* f = &xs[il * 33];
#pragma unroll
    for (int k = 0; k < 12; ++k) f[k] = cnt[k];
    f[12] = fminf(__fsqrt_rn(dmin[0]) * 0.1f, 1.0f);   // sqrt after min: bit-exact
    f[13] = fminf(__fsqrt_rn(dmin[1]) * 0.1f, 1.0f);
    f[14] = fminf(__fsqrt_rn(dmin[2]) * 0.1f, 1.0f);
#pragma unroll
    for (int k = 0; k < 8; ++k) {
      f[15 + 2 * k] = scnt[k];
      f[16 + 2 * k] = fminf(__fsqrt_rn(smin[k]) * 0.1f, 1.0f);
    }
    f[31] = cnt[9] + cnt[10] + cnt[11];
    f[32] = fminf(sumd / vcnt * 0.1f, 1.0f);
  }

  // ======================= MLP (r11, unchanged) =======================
  const int w = tid >> 6;
  const int l = tid & 63;
  const float* __restrict__ xsf = xs + w * (RPW * 33);

  float xreg[5];
#pragma unroll
  for (int c = 0; c < 4; ++c) xreg[c] = xsf[c * 64 + l];
  xreg[4] = (l < 8) ? xsf[256 + l] : 0.0f;

  const v2f b1v = ((const v2f*)b1)[l];
  const v2f gav = ((const v2f*)gamma)[l];
  const v2f bev = ((const v2f*)beta)[l];
  const v2f* __restrict__ W1v = (const v2f*)W1;

  // ---- phase 1: h = x @ W1 + b1 (readlane broadcast + packed fma) ----
  v2f h[RPW];
#pragma unroll
  for (int r = 0; r < RPW; ++r) h[r] = b1v;
#pragma unroll
  for (int k = 0; k < 33; ++k) {
    const v2f wv = W1v[k * 64 + l];
#pragma unroll
    for (int r = 0; r < RPW; ++r) {
      const int v = r * 33 + k;
      pk_fma(h[r], rdlane(xreg[v >> 6], v & 63), wv);
    }
  }

  // ---- phase 2: LayerNorm + exact GELU ----
  float g0[RPW], g1[RPW];
#pragma unroll
  for (int r = 0; r < RPW; ++r) {
    float s = h[r].x + h[r].y;
#pragma unroll
    for (int o = 32; o > 0; o >>= 1) s += __shfl_xor(s, o);
    const float mu = s * 0.0078125f;
    const float d0 = h[r].x - mu, d1 = h[r].y - mu;
    float v = d0 * d0 + d1 * d1;
#pragma unroll
    for (int o = 32; o > 0; o >>= 1) v += __shfl_xor(v, o);
    const float inv = 1.0f / __fsqrt_rn(v * 0.0078125f + 1e-5f);
    float a = d0 * inv * gav.x + bev.x;
    float bb = d1 * inv * gav.y + bev.y;
    g0[r] = 0.5f * a * (1.0f + erff(a * 0.70710678118654752f));
    g1[r] = 0.5f * bb * (1.0f + erff(bb * 0.70710678118654752f));
  }

  // ---- alias barrier: scru/xs reads done (xreg loaded); gT overlays shbuf --
  __syncthreads();
  unsigned short* gThi = (unsigned short*)shbuf;    // 32 rows x stride 136
  unsigned short* gTlo = gThi + 32 * 136;           // total 17408 B = shbuf
#pragma unroll
  for (int r = 0; r < RPW; ++r) {
    const unsigned short h0 = f2bf(g0[r]);
    const unsigned short h1 = f2bf(g1[r]);
    const unsigned short l0 = f2bf(g0[r] - bf2f(h0));
    const unsigned short l1 = f2bf(g1[r] - bf2f(h1));
    const int row = RPW * w + r;
    *(unsigned*)&gThi[row * 136 + 2 * l] = (unsigned)h0 | ((unsigned)h1 << 16);
    *(unsigned*)&gTlo[row * 136 + 2 * l] = (unsigned)l0 | ((unsigned)l1 << 16);
  }
  __syncthreads();   // cross-wave: A-frags read rows written by other waves

  // ---- phase 3: out = g @ W2 + b2 via MFMA (split-bf16, 3 products) ----
  const int mt = w & 1;            // M-tile (16 rows)
  const int ntb = (w >> 1) * 4;    // first of 4 N-tiles
  const int q = l >> 4, ln = l & 15;
  const int arow = mt * 16 + ln;

  f32x4 acc[4];
#pragma unroll
  for (int t = 0; t < 4; ++t) {
    const float bv = b2[(ntb + t) * 16 + ln];
    acc[t] = (f32x4){bv, bv, bv, bv};
  }
  const bf16x8* __restrict__ Bhi = (const bf16x8*)w2p;
  const bf16x8* __restrict__ Blo = Bhi + 2048;
#pragma unroll
  for (int kk = 0; kk < 4; ++kk) {
    const bf16x8 Ah = *(const bf16x8*)&gThi[arow * 136 + kk * 32 + q * 8];
    const bf16x8 Al = *(const bf16x8*)&gTlo[arow * 136 + kk * 32 + q * 8];
#pragma unroll
    for (int t = 0; t < 4; ++t) {
      const int fi = ((ntb + t) * 4 + kk) * 64 + l;
      const bf16x8 Bh = Bhi[fi];
      const bf16x8 Bl = Blo[fi];
      acc[t] = __builtin_amdgcn_mfma_f32_16x16x32_bf16(Ah, Bh, acc[t], 0, 0, 0);
      acc[t] = __builtin_amdgcn_mfma_f32_16x16x32_bf16(Ah, Bl, acc[t], 0, 0, 0);
      acc[t] = __builtin_amdgcn_mfma_f32_16x16x32_bf16(Al, Bh, acc[t], 0, 0, 0);
    }
  }
  const int gr0 = blockIdx.x * 32 + mt * 16 + q * 4;   // D row = quad*4 + reg
#pragma unroll
  for (int t = 0; t < 4; ++t) {
    const int col = (ntb + t) * 16 + ln;                // D col = lane&15
#pragma unroll
    for (int rg = 0; rg < 4; ++rg)
      out[(size_t)(gr0 + rg) * 128 + col] = acc[t][rg];
  }
}

extern "C" void kernel_launch(void* const* d_in, const int* in_sizes, int n_in,
                              void* d_out, int out_size, void* d_ws, size_t ws_size,
                              hipStream_t stream) {
  const float* positions = (const float*)d_in[0];
  const void*  kpm_raw   = d_in[1];
  const float* W1    = (const float*)d_in[2];
  const float* b1    = (const float*)d_in[3];
  const float* gamma = (const float*)d_in[4];
  const float* beta  = (const float*)d_in[5];
  const float* W2    = (const float*)d_in[6];
  const float* b2    = (const float*)d_in[7];
  float* out = (float*)d_out;
  unsigned short* w2p = (unsigned short*)d_ws;   // 64 KB: hi/lo bf16 B-frag planes

  w2prep<<<8, 256, 0, stream>>>(W2, w2p);
  fused_kernel<<<NBATCH * 16, 256, 0, stream>>>(positions, kpm_raw,
      W1, b1, gamma, beta, w2p, b2, out);
}

// Round 14
// 123.764 us; speedup vs baseline: 1.0380x; 1.0380x over previous
//
#include <hip/hip_runtime.h>
#include <math.h>

#define NPTS 512
#define NBATCH 64
#define NROWS (NPTS * NBATCH)   // 32768
#define LARGEV 1000000.0f
#define RPW 8                   // rows per wave in the MLP phases

typedef float v2f __attribute__((ext_vector_type(2)));
typedef short bf16x8 __attribute__((ext_vector_type(8)));   // 8 bf16 = 4 VGPRs
typedef float f32x4 __attribute__((ext_vector_type(4)));

__device__ __forceinline__ float rdlane(float v, int l) {
  return __uint_as_float((unsigned)__builtin_amdgcn_readlane((int)__float_as_uint(v), l));
}
__device__ __forceinline__ void pk_fma(v2f& acc, float s, v2f w) {
  acc = __builtin_elementwise_fma(w, (v2f){s, s}, acc);
}
// manual bf16 RTNE; inputs finite here
__device__ __forceinline__ unsigned short f2bf(float f) {
  unsigned u = __float_as_uint(f);
  u += 0x7FFFu + ((u >> 16) & 1u);
  return (unsigned short)(u >> 16);
}
__device__ __forceinline__ float bf2f(unsigned short h) {
  return __uint_as_float(((unsigned)h) << 16);
}

// ---------------------------------------------------------------------------
// W2 pre-split into MFMA B-fragment order (hi/lo bf16 planes in d_ws).
// (r11-verified)
// ---------------------------------------------------------------------------
__global__ __launch_bounds__(256) void w2prep(const float* __restrict__ W2,
                                              unsigned short* __restrict__ w2p) {
  const int t = blockIdx.x * 256 + threadIdx.x;   // 0..2047
  const int lane = t & 63;
  const int kk = (t >> 6) & 3;
  const int nt = t >> 8;                           // 0..7
  const int n  = nt * 16 + (lane & 15);
  const int k0 = kk * 32 + ((lane >> 4) << 3);
  unsigned hv[4], lv[4];
#pragma unroll
  for (int jp = 0; jp < 4; ++jp) {
    const float va = W2[(k0 + 2 * jp) * 128 + n];
    const float vb = W2[(k0 + 2 * jp + 1) * 128 + n];
    const unsigned short ha = f2bf(va), hb = f2bf(vb);
    const unsigned short la = f2bf(va - bf2f(ha)), lb = f2bf(vb - bf2f(hb));
    hv[jp] = (unsigned)ha | ((unsigned)hb << 16);
    lv[jp] = (unsigned)la | ((unsigned)lb << 16);
  }
  const int fi = (nt * 4 + kk) * 64 + lane;
  ((uint4*)w2p)[fi] = make_uint4(hv[0], hv[1], hv[2], hv[3]);
  ((uint4*)(w2p + 16384))[fi] = make_uint4(lv[0], lv[1], lv[2], lv[3]);
}

// ---------------------------------------------------------------------------
// Round-14 = r11 (measured best: 59us kernel / 124.5us wall) restored, plus
// ONLY the two strictly-pipe-positive r13 pieces:
//  - sp staged-read as float4 (2 points / ds_read_b128, zero VALU cost)
//  - dir mins in registers in d^2 domain (bit-exact via sqrt monotonicity;
//    removes 1 DS atomic/pair; dir planes dropped -> scru 18.4KB)
// r13 lesson: packed-register sector counts traded a free DS atomic for
// +8 VALU/pair and regressed 6% -- sector count/min stay as r11 DS atomics.
// Everything else (thresholds in d^2, NaN masking, readlane phase 1, LN,
// split-bf16 MFMA phase 3 with r11-verified fragment layouts) unchanged.
// ---------------------------------------------------------------------------
__global__ __launch_bounds__(256, 4) void fused_kernel(const float* __restrict__ pos,
    const void* __restrict__ kpm,
    const float* __restrict__ W1, const float* __restrict__ b1,
    const float* __restrict__ gamma, const float* __restrict__ beta,
    const unsigned short* __restrict__ w2p, const float* __restrict__ b2,
    float* __restrict__ out) {
  __shared__ __align__(16) float2 sp[NPTS];            //  4096 B
  __shared__ __align__(16) unsigned scru[18 * 256];    // 18432 B: [0..8] sector min, [9..17] count
  __shared__ float xs[32 * 33];                        //  4224 B
  __shared__ int sflag, sMasked;
  const int b  = blockIdx.x >> 4;
  const int i0 = (blockIdx.x & 15) << 5;
  const int tid = threadIdx.x;

  // ---- inline mask-dtype sniff over first 2KB of the raw mask buffer ----
  if (tid == 0) { sflag = 0; sMasked = 0; }
  __syncthreads();
  {
    const unsigned int* rw = (const unsigned int*)kpm;
    const unsigned int w0 = rw[tid];
    const unsigned int w1 = rw[tid + 256];
    int f = 0;
    if (w0 == 0x3f800000u || w1 == 0x3f800000u) f |= 2;
    if (w0 > 1u || w1 > 1u) f |= 1;
    if (f) atomicOr(&sflag, f);
  }
  __syncthreads();
  const int fmt = sflag;   // 2=>f32, 1=>bytes, 0=>i32

  // ---- stage positions (NaN for masked), count masked via ballot ----
  for (int t = tid; t < NPTS; t += 256) {
    bool m;
    if (fmt & 2)      m = ((const float*)kpm)[b * NPTS + t] != 0.0f;
    else if (fmt & 1) m = ((const unsigned char*)kpm)[b * NPTS + t] != 0;
    else              m = ((const int*)kpm)[b * NPTS + t] != 0;
    float2 p = ((const float2*)pos)[b * NPTS + t];
    if (m) { p.x = __builtin_nanf(""); p.y = p.x; }
    sp[t] = p;
    unsigned long long bal = __ballot(m);
    if ((tid & 63) == 0) atomicAdd(&sMasked, __popcll(bal));
  }
#pragma unroll
  for (int k = 0; k < 9; ++k) {
    scru[k * 256 + tid] = __float_as_uint(LARGEV);
    scru[2304 + k * 256 + tid] = 0u;
  }
  __syncthreads();
  const int M = sMasked;

  const int il = tid >> 3;       // row within block: 0..31
  const int jc = tid & 7;        // j-chunk: 0..7
  const int i  = i0 + il;
  const float2 pi = ((const float2*)pos)[b * NPTS + i];

  const float T5 = __uint_as_float(0x41C7FFFFu);   // 25 - 2^-19
  unsigned cu = 0u, cd = 0u, asum = 0u;
  float dm0 = LARGEV, dm1 = LARGEV, dm2 = LARGEV;  // dir mins in d^2 domain
  float sumd = 0.0f;
  const float4* __restrict__ sp4 = (const float4*)sp;

#pragma unroll 4
  for (int jj = 0; jj < 32; ++jj) {
    const int p = (jj << 3) + jc;          // point-pair index
    const float4 pj2 = sp4[p];             // points 2p, 2p+1
#pragma unroll
    for (int s = 0; s < 2; ++s) {
      const int j = 2 * p + s;
      const float px = s ? pj2.z : pj2.x;
      const float py = s ? pj2.w : pj2.y;
      const float dx = __fsub_rn(px, pi.x);
      const float dy = __fsub_rn(py, pi.y);
      float d2 = __fadd_rn(__fadd_rn(__fmul_rn(dx, dx), __fmul_rn(dy, dy)), 1e-8f);
      d2 = (j == i) ? __builtin_nanf("") : d2;     // self -> NaN

      const float hdy = __fmul_rn(fabsf(dy), 0.5f);
      const bool up = dx > hdy;
      const bool dn = dx < -hdy;

      const unsigned a = (d2 < 9.0f)  ? 0x01010101u
                       : ((d2 < T5)    ? 0x01010100u
                       : ((d2 < 64.0f) ? 0x01010000u
                       : ((d2 < 144.0f) ? 0x01000000u : 0u)));
      asum += a;
      cu += up ? a : 0u;
      cd += dn ? a : 0u;

      // dir mins in d^2 (bit-exact: sqrt monotone; NaN dropped by minNum)
      dm0 = fminf(dm0, up ? d2 : LARGEV);
      dm1 = fminf(dm1, dn ? d2 : LARGEV);
      dm2 = fminf(dm2, (!up && !dn) ? d2 : LARGEV);

      const float dist = __fsqrt_rn(d2);           // NaN-propagating
      sumd += (dist < 1.0e30f) ? dist : 0.0f;

      // octant sector; dy==0,dx>0 -> s4; dy==0,dx<=0 / NaN -> 8 (trash)
      const int slot = (dy > 0.0f)
          ? ((dx > 0.0f) ? ((dy < dx) ? 4 : 5) : ((-dx < dy) ? 6 : 7))
          : ((dy < 0.0f) ? ((dx < 0.0f) ? ((dx < dy) ? 0 : 1) : ((dx < -dy) ? 2 : 3))
                         : ((dx > 0.0f) ? 4 : 8));
      const int idx = slot * 256 + tid;
      atomicMin(&scru[idx], __float_as_uint(dist));   // ds_min_u32, no return
      atomicAdd(&scru[2304 + idx], 1u);               // ds_add_u32, no return
    }
  }

  // ---- readback own sector cells + unpack ----
  const unsigned clp = asum - cu - cd;
  float cnt[12];
  cnt[0] = (float)(cu & 0xffu);  cnt[3] = (float)((cu >> 8) & 0xffu);
  cnt[6] = (float)((cu >> 16) & 0xffu);  cnt[9]  = (float)(cu >> 24);
  cnt[1] = (float)(cd & 0xffu);  cnt[4] = (float)((cd >> 8) & 0xffu);
  cnt[7] = (float)((cd >> 16) & 0xffu);  cnt[10] = (float)(cd >> 24);
  cnt[2] = (float)(clp & 0xffu); cnt[5] = (float)((clp >> 8) & 0xffu);
  cnt[8] = (float)((clp >> 16) & 0xffu); cnt[11] = (float)(clp >> 24);
  float scnt[8], smin[8];
#pragma unroll
  for (int k = 0; k < 8; ++k) {
    smin[k] = __uint_as_float(scru[k * 256 + tid]);
    scnt[k] = (float)scru[2304 + k * 256 + tid];
  }
  float dmin[3] = {dm0, dm1, dm2};

  // ---- reduce 8 chunk partials (lanes differing in bits 0..2) ----
#pragma unroll
  for (int k = 0; k < 12; ++k) {
    cnt[k] += __shfl_xor(cnt[k], 1); cnt[k] += __shfl_xor(cnt[k], 2); cnt[k] += __shfl_xor(cnt[k], 4);
  }
#pragma unroll
  for (int k = 0; k < 8; ++k) {
    scnt[k] += __shfl_xor(scnt[k], 1); scnt[k] += __shfl_xor(scnt[k], 2); scnt[k] += __shfl_xor(scnt[k], 4);
  }
  sumd += __shfl_xor(sumd, 1); sumd += __shfl_xor(sumd, 2); sumd += __shfl_xor(sumd, 4);
#pragma unroll
  for (int k = 0; k < 3; ++k) {
    dmin[k] = fminf(dmin[k], __shfl_xor(dmin[k], 1));
    dmin[k] = fminf(dmin[k], __shfl_xor(dmin[k], 2));
    dmin[k] = fminf(dmin[k], __shfl_xor(dmin[k], 4));
  }
#pragma unroll
  for (int k = 0; k < 8; ++k) {
    smin[k] = fminf(smin[k], __shfl_xor(smin[k], 1));
    smin[k] = fminf(smin[k], __shfl_xor(smin[k], 2));
    smin[k] = fminf(smin[k], __shfl_xor(smin[k], 4));
  }

  // ---- park row il's 33 feats (same-wave handoff, r11-proven) ----
  if (jc == 0) {
    const bool own_unmasked = !isnan(sp[i].x);
    const float vcnt = fmaxf((float)(NPTS - M - (own_unmasked ? 1 : 0)), 1.0f);
    float* f = &xs[il * 33];
#pragma unroll
    for (int k = 0; k < 12; ++k) f[k] = cnt[k];
    f[12] = fminf(__fsqrt_rn(dmin[0]) * 0.1f, 1.0f);   // sqrt after min: bit-exact
    f[13] = fminf(__fsqrt_rn(dmin[1]) * 0.1f, 1.0f);
    f[14] = fminf(__fsqrt_rn(dmin[2]) * 0.1f, 1.0f);
#pragma unroll
    for (int k = 0; k < 8; ++k) {
      f[15 + 2 * k] = scnt[k];
      f[16 + 2 * k] = fminf(smin[k] * 0.1f, 1.0f);
    }
    f[31] = cnt[9] + cnt[10] + cnt[11];
    f[32] = fminf(sumd / vcnt * 0.1f, 1.0f);
  }

  // ======================= MLP (r11, unchanged) =======================
  const int w = tid >> 6;
  const int l = tid & 63;
  const float* __restrict__ xsf = xs + w * (RPW * 33);

  float xreg[5];
#pragma unroll
  for (int c = 0; c < 4; ++c) xreg[c] = xsf[c * 64 + l];
  xreg[4] = (l < 8) ? xsf[256 + l] : 0.0f;

  const v2f b1v = ((const v2f*)b1)[l];
  const v2f gav = ((const v2f*)gamma)[l];
  const v2f bev = ((const v2f*)beta)[l];
  const v2f* __restrict__ W1v = (const v2f*)W1;

  // ---- phase 1: h = x @ W1 + b1 (readlane broadcast + packed fma) ----
  v2f h[RPW];
#pragma unroll
  for (int r = 0; r < RPW; ++r) h[r] = b1v;
#pragma unroll
  for (int k = 0; k < 33; ++k) {
    const v2f wv = W1v[k * 64 + l];
#pragma unroll
    for (int r = 0; r < RPW; ++r) {
      const int v = r * 33 + k;
      pk_fma(h[r], rdlane(xreg[v >> 6], v & 63), wv);
    }
  }

  // ---- phase 2: LayerNorm + exact GELU ----
  float g0[RPW], g1[RPW];
#pragma unroll
  for (int r = 0; r < RPW; ++r) {
    float s = h[r].x + h[r].y;
#pragma unroll
    for (int o = 32; o > 0; o >>= 1) s += __shfl_xor(s, o);
    const float mu = s * 0.0078125f;
    const float d0 = h[r].x - mu, d1 = h[r].y - mu;
    float v = d0 * d0 + d1 * d1;
#pragma unroll
    for (int o = 32; o > 0; o >>= 1) v += __shfl_xor(v, o);
    const float inv = 1.0f / __fsqrt_rn(v * 0.0078125f + 1e-5f);
    float a = d0 * inv * gav.x + bev.x;
    float bb = d1 * inv * gav.y + bev.y;
    g0[r] = 0.5f * a * (1.0f + erff(a * 0.70710678118654752f));
    g1[r] = 0.5f * bb * (1.0f + erff(bb * 0.70710678118654752f));
  }

  // ---- alias barrier: all scru reads done above; gT overlays scru ----
  __syncthreads();
  unsigned short* gThi = (unsigned short*)scru;     // 32 rows x stride 136
  unsigned short* gTlo = gThi + 32 * 136;           // total 17408 B <= 18432 B
#pragma unroll
  for (int r = 0; r < RPW; ++r) {
    const unsigned short h0 = f2bf(g0[r]);
    const unsigned short h1 = f2bf(g1[r]);
    const unsigned short l0 = f2bf(g0[r] - bf2f(h0));
    const unsigned short l1 = f2bf(g1[r] - bf2f(h1));
    const int row = RPW * w + r;
    *(unsigned*)&gThi[row * 136 + 2 * l] = (unsigned)h0 | ((unsigned)h1 << 16);
    *(unsigned*)&gTlo[row * 136 + 2 * l] = (unsigned)l0 | ((unsigned)l1 << 16);
  }
  __syncthreads();   // cross-wave: A-frags read rows written by other waves

  // ---- phase 3: out = g @ W2 + b2 via MFMA (split-bf16, 3 products) ----
  const int mt = w & 1;            // M-tile (16 rows)
  const int ntb = (w >> 1) * 4;    // first of 4 N-tiles
  const int q = l >> 4, ln = l & 15;
  const int arow = mt * 16 + ln;

  f32x4 acc[4];
#pragma unroll
  for (int t = 0; t < 4; ++t) {
    const float bv = b2[(ntb + t) * 16 + ln];
    acc[t] = (f32x4){bv, bv, bv, bv};
  }
  const bf16x8* __restrict__ Bhi = (const bf16x8*)w2p;
  const bf16x8* __restrict__ Blo = Bhi + 2048;
#pragma unroll
  for (int kk = 0; kk < 4; ++kk) {
    const bf16x8 Ah = *(const bf16x8*)&gThi[arow * 136 + kk * 32 + q * 8];
    const bf16x8 Al = *(const bf16x8*)&gTlo[arow * 136 + kk * 32 + q * 8];
#pragma unroll
    for (int t = 0; t < 4; ++t) {
      const int fi = ((ntb + t) * 4 + kk) * 64 + l;
      const bf16x8 Bh = Bhi[fi];
      const bf16x8 Bl = Blo[fi];
      acc[t] = __builtin_amdgcn_mfma_f32_16x16x32_bf16(Ah, Bh, acc[t], 0, 0, 0);
      acc[t] = __builtin_amdgcn_mfma_f32_16x16x32_bf16(Ah, Bl, acc[t], 0, 0, 0);
      acc[t] = __builtin_amdgcn_mfma_f32_16x16x32_bf16(Al, Bh, acc[t], 0, 0, 0);
    }
  }
  const int gr0 = blockIdx.x * 32 + mt * 16 + q * 4;   // D row = quad*4 + reg
#pragma unroll
  for (int t = 0; t < 4; ++t) {
    const int col = (ntb + t) * 16 + ln;                // D col = lane&15
#pragma unroll
    for (int rg = 0; rg < 4; ++rg)
      out[(size_t)(gr0 + rg) * 128 + col] = acc[t][rg];
  }
}

extern "C" void kernel_launch(void* const* d_in, const int* in_sizes, int n_in,
                              void* d_out, int out_size, void* d_ws, size_t ws_size,
                              hipStream_t stream) {
  const float* positions = (const float*)d_in[0];
  const void*  kpm_raw   = d_in[1];
  const float* W1    = (const float*)d_in[2];
  const float* b1    = (const float*)d_in[3];
  const float* gamma = (const float*)d_in[4];
  const float* beta  = (const float*)d_in[5];
  const float* W2    = (const float*)d_in[6];
  const float* b2    = (const float*)d_in[7];
  float* out = (float*)d_out;
  unsigned short* w2p = (unsigned short*)d_ws;   // 64 KB: hi/lo bf16 B-frag planes

  w2prep<<<8, 256, 0, stream>>>(W2, w2p);
  fused_kernel<<<NBATCH * 16, 256, 0, stream>>>(positions, kpm_raw,
      W1, b1, gamma, beta, w2p, b2, out);
}